// Round 3
// baseline (1788.986 us; speedup 1.0000x reference)
//
#include <hip/hip_runtime.h>
#include <hip/hip_bf16.h>

typedef __attribute__((ext_vector_type(8))) short bf16x8;
typedef __attribute__((ext_vector_type(4))) float f32x4;

static __device__ __forceinline__ short f2bf(float v) {
  union { float f; unsigned u; } c; c.f = v;
  unsigned r = c.u + 0x7fffu + ((c.u >> 16) & 1u);   // RNE
  return (short)(r >> 16);
}

// ---------------- degree / norm ----------------
__global__ void deg_init(float* deg, int n) {
  int i = blockIdx.x * blockDim.x + threadIdx.x;
  if (i < n) deg[i] = 1.0f;                 // self loop
}
__global__ void deg_accum(const int* __restrict__ dst, float* deg, int e) {
  int i = blockIdx.x * blockDim.x + threadIdx.x;
  if (i < e) atomicAdd(&deg[dst[i]], 1.0f);
}
__global__ void make_dinv(float* deg, int n) {
  int i = blockIdx.x * blockDim.x + threadIdx.x;
  if (i < n) deg[i] = rsqrtf(deg[i]);       // deg >= 1 always
}

// ---------------- GEMM0: [n,512] x [512,32], bf16 MFMA ----------------
__global__ __launch_bounds__(256) void gemm0_mfma(
    const float* __restrict__ x, const float* __restrict__ W,
    float* __restrict__ h, int n) {
  __shared__ bf16x8 wp[2048];               // [ct(2)][ks(16)][lane(64)], 32KB
  int tid = threadIdx.x;
  for (int s = tid; s < 2048; s += 256) {
    int ct = s >> 10, rem = s & 1023, ks = rem >> 6, lane = rem & 63;
    int r = lane & 15, half = lane >> 4;
    int k0 = ks * 32 + half * 8;
    bf16x8 tmp;
#pragma unroll
    for (int j = 0; j < 8; ++j)
      tmp[j] = f2bf(W[(k0 + j) * 32 + ct * 16 + r]);
    wp[s] = tmp;
  }
  __syncthreads();
  int wave = tid >> 6, lane = tid & 63;
  int rowbase = blockIdx.x * 64 + wave * 16;
  int r = lane & 15, half = lane >> 4;
  int arow = rowbase + r; if (arow > n - 1) arow = n - 1;
  const float* xr = x + (size_t)arow * 512 + half * 8;
  f32x4 acc0 = {0.f, 0.f, 0.f, 0.f}, acc1 = {0.f, 0.f, 0.f, 0.f};
#pragma unroll
  for (int ks = 0; ks < 16; ++ks) {
    f32x4 a0 = *(const f32x4*)(xr + ks * 32);
    f32x4 a1 = *(const f32x4*)(xr + ks * 32 + 4);
    bf16x8 af;
    af[0] = f2bf(a0[0]); af[1] = f2bf(a0[1]); af[2] = f2bf(a0[2]); af[3] = f2bf(a0[3]);
    af[4] = f2bf(a1[0]); af[5] = f2bf(a1[1]); af[6] = f2bf(a1[2]); af[7] = f2bf(a1[3]);
    acc0 = __builtin_amdgcn_mfma_f32_16x16x32_bf16(af, wp[ks * 64 + lane], acc0, 0, 0, 0);
    acc1 = __builtin_amdgcn_mfma_f32_16x16x32_bf16(af, wp[1024 + ks * 64 + lane], acc1, 0, 0, 0);
  }
#pragma unroll
  for (int rg = 0; rg < 4; ++rg) {
    int row = rowbase + half * 4 + rg;      // C/D: col=lane&15, row=(lane>>4)*4+reg
    if (row < n) {
      h[(size_t)row * 32 + r]      = acc0[rg];
      h[(size_t)row * 32 + 16 + r] = acc1[rg];
    }
  }
}

// ---------------- aggregation ----------------
template <int F>
__global__ void agg_init(const float* __restrict__ h, const float* __restrict__ dinv,
                         const float* __restrict__ bias, float* __restrict__ out, int n) {
  int idx = blockIdx.x * blockDim.x + threadIdx.x;
  if (idx >= n * F) return;
  int i = idx / F, f = idx - i * F;
  float di = dinv[i];
  out[idx] = bias[f] + h[idx] * di * di;    // bias + self-loop term
}

template <int F>
__global__ void agg_edges(const float* __restrict__ h, const float* __restrict__ dinv,
                          const int* __restrict__ src, const int* __restrict__ dst,
                          float* __restrict__ out, int e) {
  int t = blockIdx.x * blockDim.x + threadIdx.x;
  int edge = t / F, f = t - edge * F;
  if (edge >= e) return;
  int s = src[edge], d = dst[edge];
  float w = dinv[s] * dinv[d];
  atomicAdd(&out[d * F + f], h[s * F + f] * w);
}

// ---------------- pairnorm ----------------
__global__ void zero_stats(float* stats) {
  if (threadIdx.x < 40) stats[threadIdx.x] = 0.f;
}
__global__ void pn_stats(const float* __restrict__ x, float* __restrict__ stats, int n) {
  // x: [n][32]; stats[0..31]=colsum, stats[32]=sumsq
  int tid = threadIdx.x;
  int gsize = gridDim.x * blockDim.x;       // multiple of 32 -> f fixed per thread
  float csum = 0.f, ssq = 0.f;
  for (int idx = blockIdx.x * blockDim.x + tid; idx < n * 32; idx += gsize) {
    float v = x[idx];
    csum += v; ssq += v * v;
  }
#pragma unroll
  for (int off = 32; off >= 1; off >>= 1) ssq += __shfl_down(ssq, off, 64);
  csum += __shfl_down(csum, 32, 64);        // fold lane f+32 into lane f
  __shared__ float scs[4 * 32];
  __shared__ float sss[4];
  int w = tid >> 6, lane = tid & 63;
  if (lane < 32) scs[w * 32 + lane] = csum;
  if (lane == 0) sss[w] = ssq;
  __syncthreads();
  if (tid < 32) atomicAdd(&stats[tid], scs[tid] + scs[32 + tid] + scs[64 + tid] + scs[96 + tid]);
  if (tid == 0) atomicAdd(&stats[32], sss[0] + sss[1] + sss[2] + sss[3]);
}
__global__ void pn_finalize(float* stats, float inv_n) {
  int f = threadIdx.x;                      // 64 threads
  float ssq = stats[32];
  float mu = (f < 32) ? stats[f] * inv_n : 0.f;
  float m2 = mu * mu;
#pragma unroll
  for (int off = 32; off >= 1; off >>= 1) m2 += __shfl_down(m2, off, 64);
  if (f < 32) stats[f] = mu;
  if (f == 0) stats[32] = rsqrtf(1e-5f + ssq * inv_n - m2);
}
__global__ void pn_apply(float* __restrict__ x, const float* __restrict__ stats, int n) {
  int idx = blockIdx.x * blockDim.x + threadIdx.x;
  if (idx >= n * 32) return;
  int f = idx & 31;
  float v = (x[idx] - stats[f]) * stats[32];
  x[idx] = v > 0.f ? v : 0.f;               // relu
}

// ---------------- small dense GEMM (K=32) ----------------
template <int FIN, int FOUT>
__global__ void gemm_small(const float* __restrict__ x, const float* __restrict__ W,
                           float* __restrict__ out, int n) {
  __shared__ float Ws[FIN * FOUT];
  for (int i = threadIdx.x; i < FIN * FOUT; i += blockDim.x) Ws[i] = W[i];
  __syncthreads();
  int t = blockIdx.x * blockDim.x + threadIdx.x;
  int i = t / FOUT, c = t - i * FOUT;
  if (i >= n) return;
  const float* xr = x + (size_t)i * FIN;
  float acc = 0.f;
#pragma unroll
  for (int k = 0; k < FIN; ++k) acc += xr[k] * Ws[k * FOUT + c];
  out[(size_t)i * FOUT + c] = acc;
}

// ---------------- launch ----------------
static inline int cdiv(long long a, long long b) { return (int)((a + b - 1) / b); }

extern "C" void kernel_launch(void* const* d_in, const int* in_sizes, int n_in,
                              void* d_out, int out_size, void* d_ws, size_t ws_size,
                              hipStream_t stream) {
  const float* x   = (const float*)d_in[0];
  const int*   ei  = (const int*)d_in[1];
  const float* W0  = (const float*)d_in[2];
  const float* b0  = (const float*)d_in[3];
  const float* W1  = (const float*)d_in[4];
  const float* b1  = (const float*)d_in[5];
  const float* Wf  = (const float*)d_in[6];
  const float* bfi = (const float*)d_in[7];
  float* out = (float*)d_out;

  int n = in_sizes[0] / 512;
  int e = in_sizes[1] / 2;
  const int* src = ei;
  const int* dst = ei + e;

  // Workspace budget (defensive: keep under ~17MB in case ws_size is small).
  // bufB ping-pong lives in d_out itself (N*40 floats >= every intermediate N*32).
  char* ws = (char*)d_ws;
  size_t o = 0;
  auto alloc = [&](size_t bytes) { char* p = ws + o; o = (o + bytes + 255) & ~(size_t)255; return p; };
  float* dinv  = (float*)alloc((size_t)n * 4);
  float* stats = (float*)alloc(256);
  float* bufA  = (float*)alloc((size_t)n * 40 * 4);
  float* bufB  = out;   // d_out doubles as ping-pong buffer; stream order prevents hazards

  // degree -> dinv
  deg_init<<<cdiv(n, 256), 256, 0, stream>>>(dinv, n);
  deg_accum<<<cdiv(e, 256), 256, 0, stream>>>(dst, dinv, e);
  make_dinv<<<cdiv(n, 256), 256, 0, stream>>>(dinv, n);

  // layer 0
  gemm0_mfma<<<cdiv(n, 64), 256, 0, stream>>>(x, W0, bufA, n);
  agg_init<32><<<cdiv((long long)n * 32, 256), 256, 0, stream>>>(bufA, dinv, b0, bufB, n);
  agg_edges<32><<<cdiv((long long)e * 32, 256), 256, 0, stream>>>(bufA, dinv, src, dst, bufB, e);
  zero_stats<<<1, 64, 0, stream>>>(stats);
  pn_stats<<<400, 256, 0, stream>>>(bufB, stats, n);
  pn_finalize<<<1, 64, 0, stream>>>(stats, 1.0f / n);
  pn_apply<<<cdiv((long long)n * 32, 256), 256, 0, stream>>>(bufB, stats, n);

  // layer 1
  gemm_small<32, 32><<<cdiv((long long)n * 32, 256), 256, 0, stream>>>(bufB, W1, bufA, n);
  agg_init<32><<<cdiv((long long)n * 32, 256), 256, 0, stream>>>(bufA, dinv, b1, bufB, n);
  agg_edges<32><<<cdiv((long long)e * 32, 256), 256, 0, stream>>>(bufA, dinv, src, dst, bufB, e);
  zero_stats<<<1, 64, 0, stream>>>(stats);
  pn_stats<<<400, 256, 0, stream>>>(bufB, stats, n);
  pn_finalize<<<1, 64, 0, stream>>>(stats, 1.0f / n);
  pn_apply<<<cdiv((long long)n * 32, 256), 256, 0, stream>>>(bufB, stats, n);

  // final layer (gemm_small consumes bufB=d_out fully before agg_init rewrites d_out)
  gemm_small<32, 40><<<cdiv((long long)n * 40, 320), 320, 0, stream>>>(bufB, Wf, bufA, n);
  agg_init<40><<<cdiv((long long)n * 40, 256), 256, 0, stream>>>(bufA, dinv, bfi, out, n);
  agg_edges<40><<<cdiv((long long)e * 40, 256), 256, 0, stream>>>(bufA, dinv, src, dst, out, e);
}

// Round 4
// 1290.673 us; speedup vs baseline: 1.3861x; 1.3861x over previous
//
#include <hip/hip_runtime.h>
#include <hip/hip_bf16.h>

typedef __attribute__((ext_vector_type(8))) short bf16x8;
typedef __attribute__((ext_vector_type(4))) float f32x4;

static __device__ __forceinline__ short f2bf(float v) {
  union { float f; unsigned u; } c; c.f = v;
  unsigned r = c.u + 0x7fffu + ((c.u >> 16) & 1u);   // RNE
  return (short)(r >> 16);
}

// ---------------- CSR build ----------------
__global__ void zero_int(int* p, int n) {
  int i = blockIdx.x * blockDim.x + threadIdx.x;
  if (i < n) p[i] = 0;
}
__global__ void count_dst(const int* __restrict__ dst, int* __restrict__ cnt, int e) {
  int i = blockIdx.x * blockDim.x + threadIdx.x;
  if (i < e) atomicAdd(&cnt[dst[i]], 1);
}
__global__ void make_dinv2(const int* __restrict__ cnt, float* __restrict__ dinv, int n) {
  int i = blockIdx.x * blockDim.x + threadIdx.x;
  if (i < n) dinv[i] = rsqrtf(1.0f + (float)cnt[i]);   // +1 self loop
}
// exclusive scan, 1024 elems/block (256 thr x 4)
__global__ __launch_bounds__(256) void scan1(const int* __restrict__ cnt, int* __restrict__ excl,
                                             int* __restrict__ blksum, int n) {
  __shared__ int tsum[256];
  int t = threadIdx.x;
  int idx = blockIdx.x * 1024 + t * 4;
  int4 v = {0, 0, 0, 0};
  if (idx + 3 < n) v = *(const int4*)(cnt + idx);
  else {
    if (idx < n) v.x = cnt[idx];
    if (idx + 1 < n) v.y = cnt[idx + 1];
    if (idx + 2 < n) v.z = cnt[idx + 2];
    if (idx + 3 < n) v.w = cnt[idx + 3];
  }
  int s = v.x + v.y + v.z + v.w;
  tsum[t] = s;
  __syncthreads();
  for (int off = 1; off < 256; off <<= 1) {
    int val = (t >= off) ? tsum[t - off] : 0;
    __syncthreads();
    tsum[t] += val;
    __syncthreads();
  }
  int e0 = tsum[t] - s;   // exclusive prefix of this thread within block
  if (idx < n) excl[idx] = e0;
  if (idx + 1 < n) excl[idx + 1] = e0 + v.x;
  if (idx + 2 < n) excl[idx + 2] = e0 + v.x + v.y;
  if (idx + 3 < n) excl[idx + 3] = e0 + v.x + v.y + v.z;
  if (t == 255) blksum[blockIdx.x] = tsum[255];
}
__global__ void scan2(const int* __restrict__ blksum, int* __restrict__ blkoff, int nb) {
  __shared__ int s[256];
  int t = threadIdx.x;
  int v0 = (t < nb) ? blksum[t] : 0;
  s[t] = v0;
  __syncthreads();
  for (int off = 1; off < 256; off <<= 1) {
    int val = (t >= off) ? s[t - off] : 0;
    __syncthreads();
    s[t] += val;
    __syncthreads();
  }
  if (t < nb) blkoff[t] = s[t] - v0;
}
__global__ void scan3(int* __restrict__ rowptr, const int* __restrict__ blkoff,
                      int* __restrict__ cursor, int n) {
  int i = blockIdx.x * blockDim.x + threadIdx.x;
  if (i < n) {
    int r = rowptr[i] + blkoff[i >> 10];
    rowptr[i] = r;
    cursor[i] = r;
  }
}
__global__ void scatter_edges(const int* __restrict__ src, const int* __restrict__ dst,
                              int* __restrict__ cursor, int* __restrict__ ssrc, int e) {
  int i = blockIdx.x * blockDim.x + threadIdx.x;
  if (i < e) {
    int p = atomicAdd(&cursor[dst[i]], 1);
    ssrc[p] = src[i];
  }
  // after this kernel, cursor[i] == row end
}

// ---------------- GEMM0: [n,512] x [512,32], bf16 MFMA, out scaled by dinv[row] ----------------
__global__ __launch_bounds__(256) void gemm0_mfma(
    const float* __restrict__ x, const float* __restrict__ W,
    const float* __restrict__ dinv, float* __restrict__ h, int n) {
  __shared__ bf16x8 wp[2048];               // [ct(2)][ks(16)][lane(64)], 32KB
  int tid = threadIdx.x;
  for (int s = tid; s < 2048; s += 256) {
    int ct = s >> 10, rem = s & 1023, ks = rem >> 6, lane = rem & 63;
    int r = lane & 15, half = lane >> 4;
    int k0 = ks * 32 + half * 8;
    bf16x8 tmp;
#pragma unroll
    for (int j = 0; j < 8; ++j)
      tmp[j] = f2bf(W[(k0 + j) * 32 + ct * 16 + r]);
    wp[s] = tmp;
  }
  __syncthreads();
  int wave = tid >> 6, lane = tid & 63;
  int rowbase = blockIdx.x * 64 + wave * 16;
  int r = lane & 15, half = lane >> 4;
  int arow = rowbase + r; if (arow > n - 1) arow = n - 1;
  const float* xr = x + (size_t)arow * 512 + half * 8;
  f32x4 acc0 = {0.f, 0.f, 0.f, 0.f}, acc1 = {0.f, 0.f, 0.f, 0.f};
#pragma unroll
  for (int ks = 0; ks < 16; ++ks) {
    f32x4 a0 = *(const f32x4*)(xr + ks * 32);
    f32x4 a1 = *(const f32x4*)(xr + ks * 32 + 4);
    bf16x8 af;
    af[0] = f2bf(a0[0]); af[1] = f2bf(a0[1]); af[2] = f2bf(a0[2]); af[3] = f2bf(a0[3]);
    af[4] = f2bf(a1[0]); af[5] = f2bf(a1[1]); af[6] = f2bf(a1[2]); af[7] = f2bf(a1[3]);
    acc0 = __builtin_amdgcn_mfma_f32_16x16x32_bf16(af, wp[ks * 64 + lane], acc0, 0, 0, 0);
    acc1 = __builtin_amdgcn_mfma_f32_16x16x32_bf16(af, wp[1024 + ks * 64 + lane], acc1, 0, 0, 0);
  }
#pragma unroll
  for (int rg = 0; rg < 4; ++rg) {
    int row = rowbase + half * 4 + rg;      // C/D: col=lane&15, row=(lane>>4)*4+reg
    if (row < n) {
      float dv = dinv[row];
      h[(size_t)row * 32 + r]      = acc0[rg] * dv;
      h[(size_t)row * 32 + 16 + r] = acc1[rg] * dv;
    }
  }
}

// ---------------- gather aggregation (h pre-scaled by dinv[src]) ----------------
// out[d] = bias + dinv[d] * ( h'[d] + sum_{s in row d} h'[s] )
__global__ __launch_bounds__(256) void agg_gather32(
    const float* __restrict__ h, const float* __restrict__ dinv,
    const float* __restrict__ bias, const int* __restrict__ rowptr,
    const int* __restrict__ rowend, const int* __restrict__ ssrc,
    float* __restrict__ out, int n) {
  int wid = (int)((blockIdx.x * 256u + threadIdx.x) >> 6);
  int lane = threadIdx.x & 63;
  if (wid >= n) return;
  int f = lane & 31;
  int r0 = rowptr[wid], r1 = rowend[wid];
  float acc = 0.f;
  for (int j = r0 + (lane >> 5); j < r1; j += 2) {
    int s = ssrc[j];
    acc += h[(size_t)s * 32 + f];
  }
  acc += __shfl_down(acc, 32, 64);
  if (lane < 32) {
    float di = dinv[wid];
    out[(size_t)wid * 32 + f] = bias[f] + di * (h[(size_t)wid * 32 + f] + acc);
  }
}
__global__ __launch_bounds__(256) void agg_gather40(
    const float* __restrict__ h, const float* __restrict__ dinv,
    const float* __restrict__ bias, const int* __restrict__ rowptr,
    const int* __restrict__ rowend, const int* __restrict__ ssrc,
    float* __restrict__ out, int n) {
  int wid = (int)((blockIdx.x * 256u + threadIdx.x) >> 6);
  int lane = threadIdx.x & 63;
  if (wid >= n) return;
  int r0 = rowptr[wid], r1 = rowend[wid];
  float acc = 0.f;
  for (int base = r0; base < r1; base += 64) {
    int myidx = base + lane;
    int sl = (myidx < r1) ? ssrc[myidx] : 0;
    int c = min(64, r1 - base);
    for (int k = 0; k < c; ++k) {
      int s = __shfl(sl, k, 64);
      if (lane < 40) acc += h[(size_t)s * 40 + lane];
    }
  }
  if (lane < 40) {
    float di = dinv[wid];
    out[(size_t)wid * 40 + lane] = bias[lane] + di * (h[(size_t)wid * 40 + lane] + acc);
  }
}

// ---------------- fallback atomic aggregation (h pre-scaled by dinv[src]) ----------------
template <int F>
__global__ void agg_init(const float* __restrict__ h, const float* __restrict__ dinv,
                         const float* __restrict__ bias, float* __restrict__ out, int n) {
  int idx = blockIdx.x * blockDim.x + threadIdx.x;
  if (idx >= n * F) return;
  int i = idx / F, f = idx - i * F;
  out[idx] = bias[f] + h[idx] * dinv[i];
}
template <int F>
__global__ void agg_edges(const float* __restrict__ h, const float* __restrict__ dinv,
                          const int* __restrict__ src, const int* __restrict__ dst,
                          float* __restrict__ out, int e) {
  int t = blockIdx.x * blockDim.x + threadIdx.x;
  int edge = t / F, f = t - edge * F;
  if (edge >= e) return;
  int s = src[edge], d = dst[edge];
  atomicAdd(&out[d * F + f], h[s * F + f] * dinv[d]);
}

// ---------------- pairnorm ----------------
__global__ void zero_stats(float* stats) {
  if (threadIdx.x < 40) stats[threadIdx.x] = 0.f;
}
__global__ void pn_stats(const float* __restrict__ x, float* __restrict__ stats, int n) {
  int tid = threadIdx.x;
  int gsize = gridDim.x * blockDim.x;
  float csum = 0.f, ssq = 0.f;
  for (int idx = blockIdx.x * blockDim.x + tid; idx < n * 32; idx += gsize) {
    float v = x[idx];
    csum += v; ssq += v * v;
  }
#pragma unroll
  for (int off = 32; off >= 1; off >>= 1) ssq += __shfl_down(ssq, off, 64);
  csum += __shfl_down(csum, 32, 64);
  __shared__ float scs[4 * 32];
  __shared__ float sss[4];
  int w = tid >> 6, lane = tid & 63;
  if (lane < 32) scs[w * 32 + lane] = csum;
  if (lane == 0) sss[w] = ssq;
  __syncthreads();
  if (tid < 32) atomicAdd(&stats[tid], scs[tid] + scs[32 + tid] + scs[64 + tid] + scs[96 + tid]);
  if (tid == 0) atomicAdd(&stats[32], sss[0] + sss[1] + sss[2] + sss[3]);
}
__global__ void pn_finalize(float* stats, float inv_n) {
  int f = threadIdx.x;
  float ssq = stats[32];
  float mu = (f < 32) ? stats[f] * inv_n : 0.f;
  float m2 = mu * mu;
#pragma unroll
  for (int off = 32; off >= 1; off >>= 1) m2 += __shfl_down(m2, off, 64);
  if (f < 32) stats[f] = mu;
  if (f == 0) stats[32] = rsqrtf(1e-5f + ssq * inv_n - m2);
}
__global__ void pn_apply(float* __restrict__ x, const float* __restrict__ stats, int n) {
  int idx = blockIdx.x * blockDim.x + threadIdx.x;
  if (idx >= n * 32) return;
  int f = idx & 31;
  float v = (x[idx] - stats[f]) * stats[32];
  x[idx] = v > 0.f ? v : 0.f;
}

// ---------------- small dense GEMM (K=32), out scaled by dinv[i] ----------------
template <int FIN, int FOUT>
__global__ void gemm_small(const float* __restrict__ x, const float* __restrict__ W,
                           const float* __restrict__ dinv, float* __restrict__ out, int n) {
  __shared__ float Ws[FIN * FOUT];
  for (int i = threadIdx.x; i < FIN * FOUT; i += blockDim.x) Ws[i] = W[i];
  __syncthreads();
  int t = blockIdx.x * blockDim.x + threadIdx.x;
  int i = t / FOUT, c = t - i * FOUT;
  if (i >= n) return;
  const float* xr = x + (size_t)i * FIN;
  float acc = 0.f;
#pragma unroll
  for (int k = 0; k < FIN; ++k) acc += xr[k] * Ws[k * FOUT + c];
  out[(size_t)i * FOUT + c] = acc * dinv[i];
}

// ---------------- launch ----------------
static inline int cdiv(long long a, long long b) { return (int)((a + b - 1) / b); }

extern "C" void kernel_launch(void* const* d_in, const int* in_sizes, int n_in,
                              void* d_out, int out_size, void* d_ws, size_t ws_size,
                              hipStream_t stream) {
  const float* x   = (const float*)d_in[0];
  const int*   ei  = (const int*)d_in[1];
  const float* W0  = (const float*)d_in[2];
  const float* b0  = (const float*)d_in[3];
  const float* W1  = (const float*)d_in[4];
  const float* b1  = (const float*)d_in[5];
  const float* Wf  = (const float*)d_in[6];
  const float* bfi = (const float*)d_in[7];
  float* out = (float*)d_out;

  int n = in_sizes[0] / 512;
  int e = in_sizes[1] / 2;
  const int* src = ei;
  const int* dst = ei + e;

  char* ws = (char*)d_ws;
  size_t o = 0;
  auto alloc = [&](size_t bytes) { char* p = ws + o; o = (o + bytes + 255) & ~(size_t)255; return p; };
  // shared allocations (both paths)
  int*   cnt   = (int*)alloc((size_t)n * 4);      // counts -> cursor -> rowend
  float* dinv  = (float*)alloc((size_t)n * 4);
  float* stats = (float*)alloc(256);
  float* bufA  = (float*)alloc((size_t)n * 40 * 4);
  size_t fallback_need = o;
  int*   rowptr = (int*)alloc((size_t)n * 4);
  int*   blksum = (int*)alloc(1024);
  int*   blkoff = (int*)alloc(1024);
  int*   ssrc   = (int*)alloc((size_t)e * 4);
  size_t csr_need = o;

  float* bufB = out;   // d_out doubles as ping-pong buffer (N*40 >= N*32)

  int nb = cdiv(n, 1024);
  bool use_csr = (ws_size >= csr_need) && (nb <= 256) && (ws_size >= fallback_need);

  // degree count + dinv (needed by both paths; producers pre-scale h by dinv[row])
  zero_int<<<cdiv(n, 256), 256, 0, stream>>>(cnt, n);
  count_dst<<<cdiv(e, 256), 256, 0, stream>>>(dst, cnt, e);
  make_dinv2<<<cdiv(n, 256), 256, 0, stream>>>(cnt, dinv, n);

  if (use_csr) {
    scan1<<<nb, 256, 0, stream>>>(cnt, rowptr, blksum, n);
    scan2<<<1, 256, 0, stream>>>(blksum, blkoff, nb);
    scan3<<<cdiv(n, 256), 256, 0, stream>>>(rowptr, blkoff, cnt, n);   // cnt becomes cursor
    scatter_edges<<<cdiv(e, 256), 256, 0, stream>>>(src, dst, cnt, ssrc, e);  // cnt becomes rowend
  }

  // layer 0
  gemm0_mfma<<<cdiv(n, 64), 256, 0, stream>>>(x, W0, dinv, bufA, n);
  if (use_csr) {
    agg_gather32<<<cdiv(n, 4), 256, 0, stream>>>(bufA, dinv, b0, rowptr, cnt, ssrc, bufB, n);
  } else {
    agg_init<32><<<cdiv((long long)n * 32, 256), 256, 0, stream>>>(bufA, dinv, b0, bufB, n);
    agg_edges<32><<<cdiv((long long)e * 32, 256), 256, 0, stream>>>(bufA, dinv, src, dst, bufB, e);
  }
  zero_stats<<<1, 64, 0, stream>>>(stats);
  pn_stats<<<400, 256, 0, stream>>>(bufB, stats, n);
  pn_finalize<<<1, 64, 0, stream>>>(stats, 1.0f / n);
  pn_apply<<<cdiv((long long)n * 32, 256), 256, 0, stream>>>(bufB, stats, n);

  // layer 1
  gemm_small<32, 32><<<cdiv((long long)n * 32, 256), 256, 0, stream>>>(bufB, W1, dinv, bufA, n);
  if (use_csr) {
    agg_gather32<<<cdiv(n, 4), 256, 0, stream>>>(bufA, dinv, b1, rowptr, cnt, ssrc, bufB, n);
  } else {
    agg_init<32><<<cdiv((long long)n * 32, 256), 256, 0, stream>>>(bufA, dinv, b1, bufB, n);
    agg_edges<32><<<cdiv((long long)e * 32, 256), 256, 0, stream>>>(bufA, dinv, src, dst, bufB, e);
  }
  zero_stats<<<1, 64, 0, stream>>>(stats);
  pn_stats<<<400, 256, 0, stream>>>(bufB, stats, n);
  pn_finalize<<<1, 64, 0, stream>>>(stats, 1.0f / n);
  pn_apply<<<cdiv((long long)n * 32, 256), 256, 0, stream>>>(bufB, stats, n);

  // final layer (gemm_small consumes bufB=d_out before agg rewrites d_out)
  gemm_small<32, 40><<<cdiv((long long)n * 40, 320), 320, 0, stream>>>(bufB, Wf, dinv, bufA, n);
  if (use_csr) {
    agg_gather40<<<cdiv(n, 4), 256, 0, stream>>>(bufA, dinv, bfi, rowptr, cnt, ssrc, out, n);
  } else {
    agg_init<40><<<cdiv((long long)n * 40, 256), 256, 0, stream>>>(bufA, dinv, bfi, out, n);
    agg_edges<40><<<cdiv((long long)e * 40, 256), 256, 0, stream>>>(bufA, dinv, src, dst, out, e);
  }
}

// Round 5
// 804.253 us; speedup vs baseline: 2.2244x; 1.6048x over previous
//
#include <hip/hip_runtime.h>
#include <hip/hip_bf16.h>

typedef __attribute__((ext_vector_type(8))) short bf16x8;
typedef __attribute__((ext_vector_type(4))) float f32x4;

#define NPB 512      // nodes per dst-bucket (9 bits)
#define EPB 8192     // edges per partition/hist block

static __device__ __forceinline__ short f2bf(float v) {
  union { float f; unsigned u; } c; c.f = v;
  unsigned r = c.u + 0x7fffu + ((c.u >> 16) & 1u);   // RNE
  return (short)(r >> 16);
}

// ---------------- generic ----------------
__global__ void zero_int(int* p, int n) {
  int i = blockIdx.x * blockDim.x + threadIdx.x;
  if (i < n) p[i] = 0;
}
__global__ void make_dinv2(const int* __restrict__ cnt, float* __restrict__ dinv, int n) {
  int i = blockIdx.x * blockDim.x + threadIdx.x;
  if (i < n) dinv[i] = rsqrtf(1.0f + (float)cnt[i]);   // +1 self loop
}

// ---------------- bucketed CSR build ----------------
__global__ __launch_bounds__(256) void bucket_hist(const int* __restrict__ dst,
                                                   int* __restrict__ bucket_cnt, int e, int nb) {
  __shared__ int lh[256];
  int t = threadIdx.x;
  lh[t] = 0;
  __syncthreads();
  int c0 = blockIdx.x * EPB, c1 = min(c0 + EPB, e);
  for (int i = c0 + t; i < c1; i += 256) atomicAdd(&lh[dst[i] >> 9], 1);
  __syncthreads();
  if (t < nb && lh[t] > 0) atomicAdd(&bucket_cnt[t], lh[t]);
}
__global__ void bucket_scan(const int* __restrict__ bucket_cnt, int* __restrict__ base,
                            int* __restrict__ gcursor, int nb, int e) {
  __shared__ int s[256];
  int t = threadIdx.x;
  int v = (t < nb) ? bucket_cnt[t] : 0;
  s[t] = v;
  __syncthreads();
  for (int off = 1; off < 256; off <<= 1) {
    int val = (t >= off) ? s[t - off] : 0;
    __syncthreads();
    s[t] += val;
    __syncthreads();
  }
  if (t < nb) { int b = s[t] - v; base[t] = b; gcursor[t] = b; }
  if (t == 0) base[nb] = e;
}
// packed entry: (local_dst[9b] << 17) | src[17b]   (requires n <= 131072)
__global__ __launch_bounds__(256) void bucket_partition(const int* __restrict__ src,
    const int* __restrict__ dst, int* __restrict__ gcursor, int* __restrict__ ebuf,
    int e, int nb) {
  __shared__ int lh[256];
  __shared__ int lbase[256];
  int t = threadIdx.x;
  lh[t] = 0;
  __syncthreads();
  int c0 = blockIdx.x * EPB, c1 = min(c0 + EPB, e);
  for (int i = c0 + t; i < c1; i += 256) atomicAdd(&lh[dst[i] >> 9], 1);
  __syncthreads();
  if (t < nb && lh[t] > 0) lbase[t] = atomicAdd(&gcursor[t], lh[t]);
  lh[t] = 0;           // becomes per-bucket rank cursor (only thread t read lh[t])
  __syncthreads();
  for (int i = c0 + t; i < c1; i += 256) {
    int d = dst[i], b = d >> 9;
    int r = atomicAdd(&lh[b], 1);
    ebuf[lbase[b] + r] = ((d & (NPB - 1)) << 17) | src[i];
  }
}
__global__ __launch_bounds__(256) void node_count(const int* __restrict__ ebuf,
    const int* __restrict__ base, int* __restrict__ cnt, int n) {
  __shared__ int lc[NPB];
  int b = blockIdx.x;
  for (int i = threadIdx.x; i < NPB; i += 256) lc[i] = 0;
  __syncthreads();
  int b0 = base[b], b1 = base[b + 1];
  for (int i = b0 + threadIdx.x; i < b1; i += 256) atomicAdd(&lc[ebuf[i] >> 17], 1);
  __syncthreads();
  int g0 = b * NPB;
  for (int i = threadIdx.x; i < NPB; i += 256)
    if (g0 + i < n) cnt[g0 + i] = lc[i];
}
// exclusive scan over n node counts -> rowptr[n+1]
__global__ __launch_bounds__(256) void scan1(const int* __restrict__ cnt, int* __restrict__ excl,
                                             int* __restrict__ blksum, int n) {
  __shared__ int tsum[256];
  int t = threadIdx.x;
  int idx = blockIdx.x * 1024 + t * 4;
  int4 v = {0, 0, 0, 0};
  if (idx + 3 < n) v = *(const int4*)(cnt + idx);
  else {
    if (idx < n) v.x = cnt[idx];
    if (idx + 1 < n) v.y = cnt[idx + 1];
    if (idx + 2 < n) v.z = cnt[idx + 2];
    if (idx + 3 < n) v.w = cnt[idx + 3];
  }
  int s = v.x + v.y + v.z + v.w;
  tsum[t] = s;
  __syncthreads();
  for (int off = 1; off < 256; off <<= 1) {
    int val = (t >= off) ? tsum[t - off] : 0;
    __syncthreads();
    tsum[t] += val;
    __syncthreads();
  }
  int e0 = tsum[t] - s;
  if (idx < n) excl[idx] = e0;
  if (idx + 1 < n) excl[idx + 1] = e0 + v.x;
  if (idx + 2 < n) excl[idx + 2] = e0 + v.x + v.y;
  if (idx + 3 < n) excl[idx + 3] = e0 + v.x + v.y + v.z;
  if (t == 255) blksum[blockIdx.x] = tsum[255];
}
__global__ void scan2(const int* __restrict__ blksum, int* __restrict__ blkoff, int nb) {
  __shared__ int s[256];
  int t = threadIdx.x;
  int v0 = (t < nb) ? blksum[t] : 0;
  s[t] = v0;
  __syncthreads();
  for (int off = 1; off < 256; off <<= 1) {
    int val = (t >= off) ? s[t - off] : 0;
    __syncthreads();
    s[t] += val;
    __syncthreads();
  }
  if (t < nb) blkoff[t] = s[t] - v0;
}
__global__ void scan3(int* __restrict__ rowptr, const int* __restrict__ blkoff, int n, int e) {
  int i = blockIdx.x * blockDim.x + threadIdx.x;
  if (i < n) rowptr[i] += blkoff[i >> 10];
  if (i == 0) rowptr[n] = e;
}
__global__ __launch_bounds__(256) void bucket_scatter(const int* __restrict__ ebuf,
    const int* __restrict__ base, const int* __restrict__ rowptr,
    int* __restrict__ ssrc, int n) {
  __shared__ int lcur[NPB];
  int b = blockIdx.x;
  int g0 = b * NPB;
  for (int i = threadIdx.x; i < NPB; i += 256)
    lcur[i] = (g0 + i < n) ? rowptr[g0 + i] : 0;
  __syncthreads();
  int b0 = base[b], b1 = base[b + 1];
  for (int i = b0 + threadIdx.x; i < b1; i += 256) {
    int p = ebuf[i];
    int pos = atomicAdd(&lcur[p >> 17], 1);
    ssrc[pos] = p & 0x1FFFF;
  }
}

// ---------------- GEMM0: [n,512] x [512,32], bf16 MFMA, out scaled by dinv[row] ----------------
__global__ __launch_bounds__(256) void gemm0_mfma(
    const float* __restrict__ x, const float* __restrict__ W,
    const float* __restrict__ dinv, float* __restrict__ h, int n) {
  __shared__ bf16x8 wp[2048];               // [ct(2)][ks(16)][lane(64)], 32KB
  int tid = threadIdx.x;
  for (int s = tid; s < 2048; s += 256) {
    int ct = s >> 10, rem = s & 1023, ks = rem >> 6, lane = rem & 63;
    int r = lane & 15, half = lane >> 4;
    int k0 = ks * 32 + half * 8;
    bf16x8 tmp;
#pragma unroll
    for (int j = 0; j < 8; ++j)
      tmp[j] = f2bf(W[(k0 + j) * 32 + ct * 16 + r]);
    wp[s] = tmp;
  }
  __syncthreads();
  int wave = tid >> 6, lane = tid & 63;
  int rowbase = blockIdx.x * 64 + wave * 16;
  int r = lane & 15, half = lane >> 4;
  int arow = rowbase + r; if (arow > n - 1) arow = n - 1;
  const float* xr = x + (size_t)arow * 512 + half * 8;
  f32x4 acc0 = {0.f, 0.f, 0.f, 0.f}, acc1 = {0.f, 0.f, 0.f, 0.f};
#pragma unroll
  for (int ks = 0; ks < 16; ++ks) {
    f32x4 a0 = *(const f32x4*)(xr + ks * 32);
    f32x4 a1 = *(const f32x4*)(xr + ks * 32 + 4);
    bf16x8 af;
    af[0] = f2bf(a0[0]); af[1] = f2bf(a0[1]); af[2] = f2bf(a0[2]); af[3] = f2bf(a0[3]);
    af[4] = f2bf(a1[0]); af[5] = f2bf(a1[1]); af[6] = f2bf(a1[2]); af[7] = f2bf(a1[3]);
    acc0 = __builtin_amdgcn_mfma_f32_16x16x32_bf16(af, wp[ks * 64 + lane], acc0, 0, 0, 0);
    acc1 = __builtin_amdgcn_mfma_f32_16x16x32_bf16(af, wp[1024 + ks * 64 + lane], acc1, 0, 0, 0);
  }
#pragma unroll
  for (int rg = 0; rg < 4; ++rg) {
    int row = rowbase + half * 4 + rg;      // C/D: col=lane&15, row=(lane>>4)*4+reg
    if (row < n) {
      float dv = dinv[row];
      h[(size_t)row * 32 + r]      = acc0[rg] * dv;
      h[(size_t)row * 32 + 16 + r] = acc1[rg] * dv;
    }
  }
}

// ---------------- gather aggregation (h pre-scaled by dinv[src]) ----------------
// out[d] = bias + dinv[d] * ( h'[d] + sum_{s in row d} h'[s] )
__global__ __launch_bounds__(256) void agg_gather32(
    const float* __restrict__ h, const float* __restrict__ dinv,
    const float* __restrict__ bias, const int* __restrict__ rowptr,
    const int* __restrict__ ssrc, float* __restrict__ out, int n) {
  int wid = (int)((blockIdx.x * 256u + threadIdx.x) >> 6);
  int lane = threadIdx.x & 63;
  if (wid >= n) return;
  int f = lane & 31;
  int r0 = rowptr[wid], r1 = rowptr[wid + 1];
  float self = h[(size_t)wid * 32 + f];
  float acc = 0.f;
  int j = r0 + (lane >> 5);
  for (; j + 6 < r1; j += 8) {            // 4 gathers in flight per half-wave
    int s0 = ssrc[j], s1 = ssrc[j + 2], s2 = ssrc[j + 4], s3 = ssrc[j + 6];
    float v0 = h[(size_t)s0 * 32 + f], v1 = h[(size_t)s1 * 32 + f];
    float v2 = h[(size_t)s2 * 32 + f], v3 = h[(size_t)s3 * 32 + f];
    acc += v0 + v1 + v2 + v3;
  }
  for (; j < r1; j += 2) acc += h[(size_t)ssrc[j] * 32 + f];
  acc += __shfl_down(acc, 32, 64);
  if (lane < 32)
    out[(size_t)wid * 32 + f] = bias[f] + dinv[wid] * (self + acc);
}
__global__ __launch_bounds__(256) void agg_gather40(
    const float* __restrict__ h, const float* __restrict__ dinv,
    const float* __restrict__ bias, const int* __restrict__ rowptr,
    const int* __restrict__ ssrc, float* __restrict__ out, int n) {
  int wid = (int)((blockIdx.x * 256u + threadIdx.x) >> 6);
  int lane = threadIdx.x & 63;
  if (wid >= n) return;
  int r0 = rowptr[wid], r1 = rowptr[wid + 1];
  float self = (lane < 40) ? h[(size_t)wid * 40 + lane] : 0.f;
  float acc = 0.f;
  int j = r0;
  for (; j + 3 < r1; j += 4) {
    int s0 = ssrc[j], s1 = ssrc[j + 1], s2 = ssrc[j + 2], s3 = ssrc[j + 3];
    if (lane < 40) {
      acc += h[(size_t)s0 * 40 + lane] + h[(size_t)s1 * 40 + lane]
           + h[(size_t)s2 * 40 + lane] + h[(size_t)s3 * 40 + lane];
    }
  }
  for (; j < r1; ++j)
    if (lane < 40) acc += h[(size_t)ssrc[j] * 40 + lane];
  if (lane < 40)
    out[(size_t)wid * 40 + lane] = bias[lane] + dinv[wid] * (self + acc);
}

// ---------------- fallback atomic path ----------------
__global__ void count_dst(const int* __restrict__ dst, int* __restrict__ cnt, int e) {
  int i = blockIdx.x * blockDim.x + threadIdx.x;
  if (i < e) atomicAdd(&cnt[dst[i]], 1);
}
template <int F>
__global__ void agg_init(const float* __restrict__ h, const float* __restrict__ dinv,
                         const float* __restrict__ bias, float* __restrict__ out, int n) {
  int idx = blockIdx.x * blockDim.x + threadIdx.x;
  if (idx >= n * F) return;
  int i = idx / F, f = idx - i * F;
  out[idx] = bias[f] + h[idx] * dinv[i];
}
template <int F>
__global__ void agg_edges(const float* __restrict__ h, const float* __restrict__ dinv,
                          const int* __restrict__ src, const int* __restrict__ dst,
                          float* __restrict__ out, int e) {
  int t = blockIdx.x * blockDim.x + threadIdx.x;
  int edge = t / F, f = t - edge * F;
  if (edge >= e) return;
  int s = src[edge], d = dst[edge];
  atomicAdd(&out[d * F + f], h[s * F + f] * dinv[d]);
}

// ---------------- pairnorm ----------------
__global__ void zero_stats(float* stats) {
  if (threadIdx.x < 40) stats[threadIdx.x] = 0.f;
}
__global__ void pn_stats(const float* __restrict__ x, float* __restrict__ stats, int n) {
  int tid = threadIdx.x;
  int gsize = gridDim.x * blockDim.x;
  float csum = 0.f, ssq = 0.f;
  for (int idx = blockIdx.x * blockDim.x + tid; idx < n * 32; idx += gsize) {
    float v = x[idx];
    csum += v; ssq += v * v;
  }
#pragma unroll
  for (int off = 32; off >= 1; off >>= 1) ssq += __shfl_down(ssq, off, 64);
  csum += __shfl_down(csum, 32, 64);
  __shared__ float scs[4 * 32];
  __shared__ float sss[4];
  int w = tid >> 6, lane = tid & 63;
  if (lane < 32) scs[w * 32 + lane] = csum;
  if (lane == 0) sss[w] = ssq;
  __syncthreads();
  if (tid < 32) atomicAdd(&stats[tid], scs[tid] + scs[32 + tid] + scs[64 + tid] + scs[96 + tid]);
  if (tid == 0) atomicAdd(&stats[32], sss[0] + sss[1] + sss[2] + sss[3]);
}
__global__ void pn_finalize(float* stats, float inv_n) {
  int f = threadIdx.x;
  float ssq = stats[32];
  float mu = (f < 32) ? stats[f] * inv_n : 0.f;
  float m2 = mu * mu;
#pragma unroll
  for (int off = 32; off >= 1; off >>= 1) m2 += __shfl_down(m2, off, 64);
  if (f < 32) stats[f] = mu;
  if (f == 0) stats[32] = rsqrtf(1e-5f + ssq * inv_n - m2);
}
__global__ void pn_apply(float* __restrict__ x, const float* __restrict__ stats, int n) {
  int idx = blockIdx.x * blockDim.x + threadIdx.x;
  if (idx >= n * 32) return;
  int f = idx & 31;
  float v = (x[idx] - stats[f]) * stats[32];
  x[idx] = v > 0.f ? v : 0.f;
}

// ---------------- small dense GEMM (K=32), out scaled by dinv[i] ----------------
template <int FIN, int FOUT>
__global__ void gemm_small(const float* __restrict__ x, const float* __restrict__ W,
                           const float* __restrict__ dinv, float* __restrict__ out, int n) {
  __shared__ float Ws[FIN * FOUT];
  for (int i = threadIdx.x; i < FIN * FOUT; i += blockDim.x) Ws[i] = W[i];
  __syncthreads();
  int t = blockIdx.x * blockDim.x + threadIdx.x;
  int i = t / FOUT, c = t - i * FOUT;
  if (i >= n) return;
  const float* xr = x + (size_t)i * FIN;
  float acc = 0.f;
#pragma unroll
  for (int k = 0; k < FIN; ++k) acc += xr[k] * Ws[k * FOUT + c];
  out[(size_t)i * FOUT + c] = acc * dinv[i];
}

// ---------------- launch ----------------
static inline int cdiv(long long a, long long b) { return (int)((a + b - 1) / b); }

extern "C" void kernel_launch(void* const* d_in, const int* in_sizes, int n_in,
                              void* d_out, int out_size, void* d_ws, size_t ws_size,
                              hipStream_t stream) {
  const float* x   = (const float*)d_in[0];
  const int*   ei  = (const int*)d_in[1];
  const float* W0  = (const float*)d_in[2];
  const float* b0  = (const float*)d_in[3];
  const float* W1  = (const float*)d_in[4];
  const float* b1  = (const float*)d_in[5];
  const float* Wf  = (const float*)d_in[6];
  const float* bfi = (const float*)d_in[7];
  float* out = (float*)d_out;

  int n = in_sizes[0] / 512;
  int e = in_sizes[1] / 2;
  const int* src = ei;
  const int* dst = ei + e;

  char* ws = (char*)d_ws;
  size_t o = 0;
  auto alloc = [&](size_t bytes) { char* p = ws + o; o = (o + bytes + 255) & ~(size_t)255; return p; };
  // fallback-path needs
  int*   cnt   = (int*)alloc((size_t)n * 4);
  float* dinv  = (float*)alloc((size_t)n * 4);
  float* stats = (float*)alloc(256);
  float* bufA  = (float*)alloc((size_t)n * 40 * 4);   // also aliased as ebuf pre-gemm0
  size_t fallback_need = o;
  // CSR-path extras
  int*   rowptr = (int*)alloc((size_t)(n + 1) * 4);
  int*   blksum = (int*)alloc(1024);
  int*   blkoff = (int*)alloc(1024);
  int*   bucket_cnt  = (int*)alloc(256 * 4);
  int*   bucket_base = (int*)alloc(257 * 4);
  int*   gcursor     = (int*)alloc(256 * 4);
  int*   ssrc   = (int*)alloc((size_t)e * 4);
  size_t csr_need = o;

  int* ebuf = (int*)bufA;   // packed (ldst,src); dead before gemm0 writes bufA
  float* bufB = out;        // d_out doubles as ping-pong buffer (N*40 >= N*32)

  int NBk = cdiv(n, NPB);       // dst buckets
  int nb2 = cdiv(n, 1024);      // scan1 blocks
  bool use_csr = (ws_size >= csr_need) && (n <= 131072) && (NBk <= 256) && (nb2 <= 256) &&
                 ((size_t)n * 40 * 4 >= (size_t)e * 4);

  if (use_csr) {
    // --- bucketed CSR build ---
    zero_int<<<1, 256, 0, stream>>>(bucket_cnt, NBk);
    bucket_hist<<<cdiv(e, EPB), 256, 0, stream>>>(dst, bucket_cnt, e, NBk);
    bucket_scan<<<1, 256, 0, stream>>>(bucket_cnt, bucket_base, gcursor, NBk, e);
    bucket_partition<<<cdiv(e, EPB), 256, 0, stream>>>(src, dst, gcursor, ebuf, e, NBk);
    node_count<<<NBk, 256, 0, stream>>>(ebuf, bucket_base, cnt, n);
    make_dinv2<<<cdiv(n, 256), 256, 0, stream>>>(cnt, dinv, n);
    scan1<<<nb2, 256, 0, stream>>>(cnt, rowptr, blksum, n);
    scan2<<<1, 256, 0, stream>>>(blksum, blkoff, nb2);
    scan3<<<cdiv(n, 256), 256, 0, stream>>>(rowptr, blkoff, n, e);
    bucket_scatter<<<NBk, 256, 0, stream>>>(ebuf, bucket_base, rowptr, ssrc, n);
  } else {
    zero_int<<<cdiv(n, 256), 256, 0, stream>>>(cnt, n);
    count_dst<<<cdiv(e, 256), 256, 0, stream>>>(dst, cnt, e);
    make_dinv2<<<cdiv(n, 256), 256, 0, stream>>>(cnt, dinv, n);
  }

  // layer 0
  gemm0_mfma<<<cdiv(n, 64), 256, 0, stream>>>(x, W0, dinv, bufA, n);
  if (use_csr) {
    agg_gather32<<<cdiv(n, 4), 256, 0, stream>>>(bufA, dinv, b0, rowptr, ssrc, bufB, n);
  } else {
    agg_init<32><<<cdiv((long long)n * 32, 256), 256, 0, stream>>>(bufA, dinv, b0, bufB, n);
    agg_edges<32><<<cdiv((long long)e * 32, 256), 256, 0, stream>>>(bufA, dinv, src, dst, bufB, e);
  }
  zero_stats<<<1, 64, 0, stream>>>(stats);
  pn_stats<<<400, 256, 0, stream>>>(bufB, stats, n);
  pn_finalize<<<1, 64, 0, stream>>>(stats, 1.0f / n);
  pn_apply<<<cdiv((long long)n * 32, 256), 256, 0, stream>>>(bufB, stats, n);

  // layer 1
  gemm_small<32, 32><<<cdiv((long long)n * 32, 256), 256, 0, stream>>>(bufB, W1, dinv, bufA, n);
  if (use_csr) {
    agg_gather32<<<cdiv(n, 4), 256, 0, stream>>>(bufA, dinv, b1, rowptr, ssrc, bufB, n);
  } else {
    agg_init<32><<<cdiv((long long)n * 32, 256), 256, 0, stream>>>(bufA, dinv, b1, bufB, n);
    agg_edges<32><<<cdiv((long long)e * 32, 256), 256, 0, stream>>>(bufA, dinv, src, dst, bufB, e);
  }
  zero_stats<<<1, 64, 0, stream>>>(stats);
  pn_stats<<<400, 256, 0, stream>>>(bufB, stats, n);
  pn_finalize<<<1, 64, 0, stream>>>(stats, 1.0f / n);
  pn_apply<<<cdiv((long long)n * 32, 256), 256, 0, stream>>>(bufB, stats, n);

  // final layer (gemm_small consumes bufB=d_out before agg rewrites d_out)
  gemm_small<32, 40><<<cdiv((long long)n * 40, 320), 320, 0, stream>>>(bufB, Wf, dinv, bufA, n);
  if (use_csr) {
    agg_gather40<<<cdiv(n, 4), 256, 0, stream>>>(bufA, dinv, bfi, rowptr, ssrc, out, n);
  } else {
    agg_init<40><<<cdiv((long long)n * 40, 256), 256, 0, stream>>>(bufA, dinv, bfi, out, n);
    agg_edges<40><<<cdiv((long long)e * 40, 256), 256, 0, stream>>>(bufA, dinv, src, dst, out, e);
  }
}

// Round 6
// 779.610 us; speedup vs baseline: 2.2947x; 1.0316x over previous
//
#include <hip/hip_runtime.h>
#include <hip/hip_bf16.h>

typedef __attribute__((ext_vector_type(8))) short bf16x8;
typedef __attribute__((ext_vector_type(4))) float f32x4;

#define NPB 512      // nodes per dst-bucket (9 bits)
#define EPB 8192     // edges per partition/hist block

static __device__ __forceinline__ short f2bf(float v) {
  __hip_bfloat16 b = __float2bfloat16(v);   // RNE; compiler emits packed cvt
  return __builtin_bit_cast(short, b);
}
static __device__ __forceinline__ float bf2f(unsigned short u) {
  union { unsigned u; float f; } c; c.u = (unsigned)u << 16; return c.f;
}

// ---------------- generic ----------------
__global__ void zero_int(int* p, int n) {
  int i = blockIdx.x * blockDim.x + threadIdx.x;
  if (i < n) p[i] = 0;
}
__global__ void make_dinv2(const int* __restrict__ cnt, float* __restrict__ dinv, int n) {
  int i = blockIdx.x * blockDim.x + threadIdx.x;
  if (i < n) dinv[i] = rsqrtf(1.0f + (float)cnt[i]);   // +1 self loop
}

// ---------------- bucketed CSR build ----------------
__global__ __launch_bounds__(256) void bucket_hist(const int* __restrict__ dst,
                                                   int* __restrict__ bucket_cnt, int e, int nb) {
  __shared__ int lh[256];
  int t = threadIdx.x;
  lh[t] = 0;
  __syncthreads();
  int c0 = blockIdx.x * EPB, c1 = min(c0 + EPB, e);
  for (int i = c0 + t; i < c1; i += 256) atomicAdd(&lh[dst[i] >> 9], 1);
  __syncthreads();
  if (t < nb && lh[t] > 0) atomicAdd(&bucket_cnt[t], lh[t]);
}
__global__ void bucket_scan(const int* __restrict__ bucket_cnt, int* __restrict__ base,
                            int* __restrict__ gcursor, int nb, int e) {
  __shared__ int s[256];
  int t = threadIdx.x;
  int v = (t < nb) ? bucket_cnt[t] : 0;
  s[t] = v;
  __syncthreads();
  for (int off = 1; off < 256; off <<= 1) {
    int val = (t >= off) ? s[t - off] : 0;
    __syncthreads();
    s[t] += val;
    __syncthreads();
  }
  if (t < nb) { int b = s[t] - v; base[t] = b; gcursor[t] = b; }
  if (t == 0) base[nb] = e;
}
// packed entry: (local_dst[9b] << 17) | src[17b]   (requires n <= 131072)
__global__ __launch_bounds__(256) void bucket_partition(const int* __restrict__ src,
    const int* __restrict__ dst, int* __restrict__ gcursor, int* __restrict__ ebuf,
    int e, int nb) {
  __shared__ int lh[256];
  __shared__ int lbase[256];
  int t = threadIdx.x;
  lh[t] = 0;
  __syncthreads();
  int c0 = blockIdx.x * EPB, c1 = min(c0 + EPB, e);
  for (int i = c0 + t; i < c1; i += 256) atomicAdd(&lh[dst[i] >> 9], 1);
  __syncthreads();
  if (t < nb && lh[t] > 0) lbase[t] = atomicAdd(&gcursor[t], lh[t]);
  lh[t] = 0;           // becomes per-bucket rank cursor
  __syncthreads();
  for (int i = c0 + t; i < c1; i += 256) {
    int d = dst[i], b = d >> 9;
    int r = atomicAdd(&lh[b], 1);
    ebuf[lbase[b] + r] = ((d & (NPB - 1)) << 17) | src[i];
  }
}
__global__ __launch_bounds__(256) void node_count(const int* __restrict__ ebuf,
    const int* __restrict__ base, int* __restrict__ cnt, float* __restrict__ dinv, int n) {
  __shared__ int lc[NPB];
  int b = blockIdx.x;
  for (int i = threadIdx.x; i < NPB; i += 256) lc[i] = 0;
  __syncthreads();
  int b0 = base[b], b1 = base[b + 1];
  for (int i = b0 + threadIdx.x; i < b1; i += 256) atomicAdd(&lc[ebuf[i] >> 17], 1);
  __syncthreads();
  int g0 = b * NPB;
  for (int i = threadIdx.x; i < NPB; i += 256)
    if (g0 + i < n) {
      int c = lc[i];
      cnt[g0 + i] = c;
      dinv[g0 + i] = rsqrtf(1.0f + (float)c);
    }
}
// exclusive scan over n node counts -> rowptr[n+1]
__global__ __launch_bounds__(256) void scan1(const int* __restrict__ cnt, int* __restrict__ excl,
                                             int* __restrict__ blksum, int n) {
  __shared__ int tsum[256];
  int t = threadIdx.x;
  int idx = blockIdx.x * 1024 + t * 4;
  int4 v = {0, 0, 0, 0};
  if (idx + 3 < n) v = *(const int4*)(cnt + idx);
  else {
    if (idx < n) v.x = cnt[idx];
    if (idx + 1 < n) v.y = cnt[idx + 1];
    if (idx + 2 < n) v.z = cnt[idx + 2];
    if (idx + 3 < n) v.w = cnt[idx + 3];
  }
  int s = v.x + v.y + v.z + v.w;
  tsum[t] = s;
  __syncthreads();
  for (int off = 1; off < 256; off <<= 1) {
    int val = (t >= off) ? tsum[t - off] : 0;
    __syncthreads();
    tsum[t] += val;
    __syncthreads();
  }
  int e0 = tsum[t] - s;
  if (idx < n) excl[idx] = e0;
  if (idx + 1 < n) excl[idx + 1] = e0 + v.x;
  if (idx + 2 < n) excl[idx + 2] = e0 + v.x + v.y;
  if (idx + 3 < n) excl[idx + 3] = e0 + v.x + v.y + v.z;
  if (t == 255) blksum[blockIdx.x] = tsum[255];
}
__global__ void scan2(const int* __restrict__ blksum, int* __restrict__ blkoff, int nb) {
  __shared__ int s[256];
  int t = threadIdx.x;
  int v0 = (t < nb) ? blksum[t] : 0;
  s[t] = v0;
  __syncthreads();
  for (int off = 1; off < 256; off <<= 1) {
    int val = (t >= off) ? s[t - off] : 0;
    __syncthreads();
    s[t] += val;
    __syncthreads();
  }
  if (t < nb) blkoff[t] = s[t] - v0;
}
__global__ void scan3(int* __restrict__ rowptr, const int* __restrict__ blkoff, int n, int e) {
  int i = blockIdx.x * blockDim.x + threadIdx.x;
  if (i < n) rowptr[i] += blkoff[i >> 10];
  if (i == 0) rowptr[n] = e;
}
__global__ __launch_bounds__(256) void bucket_scatter(const int* __restrict__ ebuf,
    const int* __restrict__ base, const int* __restrict__ rowptr,
    int* __restrict__ ssrc, int n) {
  __shared__ int lcur[NPB];
  int b = blockIdx.x;
  int g0 = b * NPB;
  for (int i = threadIdx.x; i < NPB; i += 256)
    lcur[i] = (g0 + i < n) ? rowptr[g0 + i] : 0;
  __syncthreads();
  int b0 = base[b], b1 = base[b + 1];
  for (int i = b0 + threadIdx.x; i < b1; i += 256) {
    int p = ebuf[i];
    int pos = atomicAdd(&lcur[p >> 17], 1);
    ssrc[pos] = p & 0x1FFFF;
  }
}

// ---------------- GEMM0: [n,512] x [512,32], bf16 MFMA, bf16 out scaled by dinv ----------------
__global__ __launch_bounds__(256) void gemm0_mfma(
    const float* __restrict__ x, const float* __restrict__ W,
    const float* __restrict__ dinv, unsigned short* __restrict__ hb, int n) {
  __shared__ bf16x8 wp[2048];               // [ct(2)][ks(16)][lane(64)], 32KB
  int tid = threadIdx.x;
  for (int s = tid; s < 2048; s += 256) {
    int ct = s >> 10, rem = s & 1023, ks = rem >> 6, lane = rem & 63;
    int r = lane & 15, half = lane >> 4;
    int k0 = ks * 32 + half * 8;
    bf16x8 tmp;
#pragma unroll
    for (int j = 0; j < 8; ++j)
      tmp[j] = f2bf(W[(k0 + j) * 32 + ct * 16 + r]);
    wp[s] = tmp;
  }
  __syncthreads();
  int wave = tid >> 6, lane = tid & 63;
  int rowbase = blockIdx.x * 64 + wave * 16;
  int r = lane & 15, half = lane >> 4;
  int arow = rowbase + r; if (arow > n - 1) arow = n - 1;
  const float* xr = x + (size_t)arow * 512 + half * 8;
  f32x4 acc0 = {0.f, 0.f, 0.f, 0.f}, acc1 = {0.f, 0.f, 0.f, 0.f};
#pragma unroll
  for (int ks = 0; ks < 16; ++ks) {
    f32x4 a0 = *(const f32x4*)(xr + ks * 32);
    f32x4 a1 = *(const f32x4*)(xr + ks * 32 + 4);
    bf16x8 af;
    af[0] = f2bf(a0[0]); af[1] = f2bf(a0[1]); af[2] = f2bf(a0[2]); af[3] = f2bf(a0[3]);
    af[4] = f2bf(a1[0]); af[5] = f2bf(a1[1]); af[6] = f2bf(a1[2]); af[7] = f2bf(a1[3]);
    acc0 = __builtin_amdgcn_mfma_f32_16x16x32_bf16(af, wp[ks * 64 + lane], acc0, 0, 0, 0);
    acc1 = __builtin_amdgcn_mfma_f32_16x16x32_bf16(af, wp[1024 + ks * 64 + lane], acc1, 0, 0, 0);
  }
#pragma unroll
  for (int rg = 0; rg < 4; ++rg) {
    int row = rowbase + half * 4 + rg;      // C/D: col=lane&15, row=(lane>>4)*4+reg
    if (row < n) {
      float dv = dinv[row];
      hb[(size_t)row * 32 + r]      = (unsigned short)f2bf(acc0[rg] * dv);
      hb[(size_t)row * 32 + 16 + r] = (unsigned short)f2bf(acc1[rg] * dv);
    }
  }
}

// ---------------- gather aggregation (hb = bf16, pre-scaled by dinv[src]) ----------------
// out[d] = bias + dinv[d] * ( hb[d] + sum_{s in row d} hb[s] )
__global__ __launch_bounds__(256) void agg_gather32(
    const unsigned short* __restrict__ hb, const float* __restrict__ dinv,
    const float* __restrict__ bias, const int* __restrict__ rowptr,
    const int* __restrict__ ssrc, float* __restrict__ out, int n) {
  int wid = (int)((blockIdx.x * 256u + threadIdx.x) >> 6);
  int lane = threadIdx.x & 63;
  if (wid >= n) return;
  int f = lane & 31;
  int r0 = rowptr[wid], r1 = rowptr[wid + 1];
  float self = bf2f(hb[(size_t)wid * 32 + f]);
  float acc = 0.f;
  int j = r0 + (lane >> 5);
  for (; j + 6 < r1; j += 8) {            // 4 gathers in flight per half-wave
    int s0 = ssrc[j], s1 = ssrc[j + 2], s2 = ssrc[j + 4], s3 = ssrc[j + 6];
    float v0 = bf2f(hb[(size_t)s0 * 32 + f]), v1 = bf2f(hb[(size_t)s1 * 32 + f]);
    float v2 = bf2f(hb[(size_t)s2 * 32 + f]), v3 = bf2f(hb[(size_t)s3 * 32 + f]);
    acc += v0 + v1 + v2 + v3;
  }
  for (; j < r1; j += 2) acc += bf2f(hb[(size_t)ssrc[j] * 32 + f]);
  acc += __shfl_down(acc, 32, 64);
  if (lane < 32)
    out[(size_t)wid * 32 + f] = bias[f] + dinv[wid] * (self + acc);
}
__global__ __launch_bounds__(256) void agg_gather40(
    const unsigned short* __restrict__ hb, const float* __restrict__ dinv,
    const float* __restrict__ bias, const int* __restrict__ rowptr,
    const int* __restrict__ ssrc, float* __restrict__ out, int n) {
  int wid = (int)((blockIdx.x * 256u + threadIdx.x) >> 6);
  int lane = threadIdx.x & 63;
  if (wid >= n) return;
  int r0 = rowptr[wid], r1 = rowptr[wid + 1];
  float self = (lane < 40) ? bf2f(hb[(size_t)wid * 40 + lane]) : 0.f;
  float acc = 0.f;
  int j = r0;
  for (; j + 3 < r1; j += 4) {
    int s0 = ssrc[j], s1 = ssrc[j + 1], s2 = ssrc[j + 2], s3 = ssrc[j + 3];
    if (lane < 40) {
      acc += bf2f(hb[(size_t)s0 * 40 + lane]) + bf2f(hb[(size_t)s1 * 40 + lane])
           + bf2f(hb[(size_t)s2 * 40 + lane]) + bf2f(hb[(size_t)s3 * 40 + lane]);
    }
  }
  for (; j < r1; ++j)
    if (lane < 40) acc += bf2f(hb[(size_t)ssrc[j] * 40 + lane]);
  if (lane < 40)
    out[(size_t)wid * 40 + lane] = bias[lane] + dinv[wid] * (self + acc);
}

// ---------------- fallback atomic path (bf16 hb) ----------------
__global__ void count_dst(const int* __restrict__ dst, int* __restrict__ cnt, int e) {
  int i = blockIdx.x * blockDim.x + threadIdx.x;
  if (i < e) atomicAdd(&cnt[dst[i]], 1);
}
template <int F>
__global__ void agg_init(const unsigned short* __restrict__ hb, const float* __restrict__ dinv,
                         const float* __restrict__ bias, float* __restrict__ out, int n) {
  int idx = blockIdx.x * blockDim.x + threadIdx.x;
  if (idx >= n * F) return;
  int i = idx / F, f = idx - i * F;
  out[idx] = bias[f] + bf2f(hb[idx]) * dinv[i];
}
template <int F>
__global__ void agg_edges(const unsigned short* __restrict__ hb, const float* __restrict__ dinv,
                          const int* __restrict__ src, const int* __restrict__ dst,
                          float* __restrict__ out, int e) {
  int t = blockIdx.x * blockDim.x + threadIdx.x;
  int edge = t / F, f = t - edge * F;
  if (edge >= e) return;
  int s = src[edge], d = dst[edge];
  atomicAdd(&out[d * F + f], bf2f(hb[s * F + f]) * dinv[d]);
}

// ---------------- pairnorm stats ----------------
__global__ void zero_stats(float* stats) {
  if (threadIdx.x < 40) stats[threadIdx.x] = 0.f;
}
__global__ void pn_stats(const float* __restrict__ x, float* __restrict__ stats, int n) {
  int tid = threadIdx.x;
  int gsize = gridDim.x * blockDim.x;
  float csum = 0.f, ssq = 0.f;
  for (int idx = blockIdx.x * blockDim.x + tid; idx < n * 32; idx += gsize) {
    float v = x[idx];
    csum += v; ssq += v * v;
  }
#pragma unroll
  for (int off = 32; off >= 1; off >>= 1) ssq += __shfl_down(ssq, off, 64);
  csum += __shfl_down(csum, 32, 64);
  __shared__ float scs[4 * 32];
  __shared__ float sss[4];
  int w = tid >> 6, lane = tid & 63;
  if (lane < 32) scs[w * 32 + lane] = csum;
  if (lane == 0) sss[w] = ssq;
  __syncthreads();
  if (tid < 32) atomicAdd(&stats[tid], scs[tid] + scs[32 + tid] + scs[64 + tid] + scs[96 + tid]);
  if (tid == 0) atomicAdd(&stats[32], sss[0] + sss[1] + sss[2] + sss[3]);
}
__global__ void pn_finalize(float* stats, float inv_n) {
  int f = threadIdx.x;
  float ssq = stats[32];
  float mu = (f < 32) ? stats[f] * inv_n : 0.f;
  float m2 = mu * mu;
#pragma unroll
  for (int off = 32; off >= 1; off >>= 1) m2 += __shfl_down(m2, off, 64);
  if (f < 32) stats[f] = mu;
  if (f == 0) stats[32] = rsqrtf(1e-5f + ssq * inv_n - m2);
}

// ---------------- small GEMM with fused pairnorm-apply + relu, bf16 out scaled by dinv ----------------
template <int FOUT>
__global__ void gemm_small_pn(const float* __restrict__ x, const float* __restrict__ W,
                              const float* __restrict__ stats, const float* __restrict__ dinv,
                              unsigned short* __restrict__ outb, int n) {
  __shared__ float Ws[32 * FOUT];
  __shared__ float mu[32];
  __shared__ float ssc[1];
  int t = threadIdx.x;
  for (int i = t; i < 32 * FOUT; i += blockDim.x) Ws[i] = W[i];
  if (t < 32) mu[t] = stats[t];
  if (t == 32) ssc[0] = stats[32];
  __syncthreads();
  float s = ssc[0];
  int idx = blockIdx.x * blockDim.x + t;
  int i = idx / FOUT, c = idx - i * FOUT;
  if (i >= n) return;
  const float* xr = x + (size_t)i * 32;
  float acc = 0.f;
#pragma unroll
  for (int k = 0; k < 32; ++k) {
    float v = (xr[k] - mu[k]) * s;
    v = v > 0.f ? v : 0.f;                  // relu
    acc += v * Ws[k * FOUT + c];
  }
  outb[(size_t)i * FOUT + c] = (unsigned short)f2bf(acc * dinv[i]);
}

// ---------------- launch ----------------
static inline int cdiv(long long a, long long b) { return (int)((a + b - 1) / b); }

extern "C" void kernel_launch(void* const* d_in, const int* in_sizes, int n_in,
                              void* d_out, int out_size, void* d_ws, size_t ws_size,
                              hipStream_t stream) {
  const float* x   = (const float*)d_in[0];
  const int*   ei  = (const int*)d_in[1];
  const float* W0  = (const float*)d_in[2];
  const float* b0  = (const float*)d_in[3];
  const float* W1  = (const float*)d_in[4];
  const float* b1  = (const float*)d_in[5];
  const float* Wf  = (const float*)d_in[6];
  const float* bfi = (const float*)d_in[7];
  float* out = (float*)d_out;

  int n = in_sizes[0] / 512;
  int e = in_sizes[1] / 2;
  const int* src = ei;
  const int* dst = ei + e;

  char* ws = (char*)d_ws;
  size_t o = 0;
  auto alloc = [&](size_t bytes) { char* p = ws + o; o = (o + bytes + 255) & ~(size_t)255; return p; };
  int*   cnt   = (int*)alloc((size_t)n * 4);
  float* dinv  = (float*)alloc((size_t)n * 4);
  float* stats = (float*)alloc(256);
  char*  hbuf  = alloc((size_t)n * 40 * 4);   // ebuf (e*4) / hb (n*32*2) / hb40 (n*40*2) time-share
  size_t fallback_need = o;
  int*   rowptr = (int*)alloc((size_t)(n + 1) * 4);
  int*   blksum = (int*)alloc(1024);
  int*   blkoff = (int*)alloc(1024);
  int*   bucket_cnt  = (int*)alloc(256 * 4);
  int*   bucket_base = (int*)alloc(257 * 4);
  int*   gcursor     = (int*)alloc(256 * 4);
  int*   ssrc   = (int*)alloc((size_t)e * 4);
  size_t csr_need = o;

  int* ebuf = (int*)hbuf;                       // dead before gemm0 writes hb
  unsigned short* hb   = (unsigned short*)hbuf; // n*32 bf16
  unsigned short* hb40 = (unsigned short*)hbuf; // n*40 bf16
  float* bufB = out;        // d_out doubles as fp32 ping-pong buffer (N*40 >= N*32)

  int NBk = cdiv(n, NPB);       // dst buckets
  int nb2 = cdiv(n, 1024);      // scan1 blocks
  bool use_csr = (ws_size >= csr_need) && (n <= 131072) && (NBk <= 256) && (nb2 <= 256) &&
                 ((size_t)n * 40 * 4 >= (size_t)e * 4);

  if (use_csr) {
    zero_int<<<1, 256, 0, stream>>>(bucket_cnt, NBk);
    bucket_hist<<<cdiv(e, EPB), 256, 0, stream>>>(dst, bucket_cnt, e, NBk);
    bucket_scan<<<1, 256, 0, stream>>>(bucket_cnt, bucket_base, gcursor, NBk, e);
    bucket_partition<<<cdiv(e, EPB), 256, 0, stream>>>(src, dst, gcursor, ebuf, e, NBk);
    node_count<<<NBk, 256, 0, stream>>>(ebuf, bucket_base, cnt, dinv, n);
    scan1<<<nb2, 256, 0, stream>>>(cnt, rowptr, blksum, n);
    scan2<<<1, 256, 0, stream>>>(blksum, blkoff, nb2);
    scan3<<<cdiv(n, 256), 256, 0, stream>>>(rowptr, blkoff, n, e);
    bucket_scatter<<<NBk, 256, 0, stream>>>(ebuf, bucket_base, rowptr, ssrc, n);
  } else {
    zero_int<<<cdiv(n, 256), 256, 0, stream>>>(cnt, n);
    count_dst<<<cdiv(e, 256), 256, 0, stream>>>(dst, cnt, e);
    make_dinv2<<<cdiv(n, 256), 256, 0, stream>>>(cnt, dinv, n);
  }

  // layer 0
  gemm0_mfma<<<cdiv(n, 64), 256, 0, stream>>>(x, W0, dinv, hb, n);
  if (use_csr) {
    agg_gather32<<<cdiv(n, 4), 256, 0, stream>>>(hb, dinv, b0, rowptr, ssrc, bufB, n);
  } else {
    agg_init<32><<<cdiv((long long)n * 32, 256), 256, 0, stream>>>(hb, dinv, b0, bufB, n);
    agg_edges<32><<<cdiv((long long)e * 32, 256), 256, 0, stream>>>(hb, dinv, src, dst, bufB, e);
  }
  zero_stats<<<1, 64, 0, stream>>>(stats);
  pn_stats<<<400, 256, 0, stream>>>(bufB, stats, n);
  pn_finalize<<<1, 64, 0, stream>>>(stats, 1.0f / n);

  // layer 1 (pairnorm-apply fused into gemm prologue)
  gemm_small_pn<32><<<cdiv((long long)n * 32, 256), 256, 0, stream>>>(bufB, W1, stats, dinv, hb, n);
  if (use_csr) {
    agg_gather32<<<cdiv(n, 4), 256, 0, stream>>>(hb, dinv, b1, rowptr, ssrc, bufB, n);
  } else {
    agg_init<32><<<cdiv((long long)n * 32, 256), 256, 0, stream>>>(hb, dinv, b1, bufB, n);
    agg_edges<32><<<cdiv((long long)e * 32, 256), 256, 0, stream>>>(hb, dinv, src, dst, bufB, e);
  }
  zero_stats<<<1, 64, 0, stream>>>(stats);
  pn_stats<<<400, 256, 0, stream>>>(bufB, stats, n);
  pn_finalize<<<1, 64, 0, stream>>>(stats, 1.0f / n);

  // final layer (gemm consumes bufB=d_out before agg rewrites d_out)
  gemm_small_pn<40><<<cdiv((long long)n * 40, 320), 320, 0, stream>>>(bufB, Wf, stats, dinv, hb40, n);
  if (use_csr) {
    agg_gather40<<<cdiv(n, 4), 256, 0, stream>>>(hb40, dinv, bfi, rowptr, ssrc, out, n);
  } else {
    agg_init<40><<<cdiv((long long)n * 40, 256), 256, 0, stream>>>(hb40, dinv, bfi, out, n);
    agg_edges<40><<<cdiv((long long)e * 40, 256), 256, 0, stream>>>(hb40, dinv, src, dst, out, e);
  }
}